// Round 1
// baseline (493.394 us; speedup 1.0000x reference)
//
#include <hip/hip_runtime.h>
#include <hip/hip_bf16.h>

#define S_ 128
#define N_ 384
#define CM 256
#define CH 32
#define CZ 128

typedef __attribute__((ext_vector_type(8))) __bf16 bf16x8;
typedef __attribute__((ext_vector_type(4))) float f32x4;

union pack4 { __hip_bfloat16 h[4]; uint2 u; };

// ---- Kernel P: fused weight prep -----------------------------------------
// blocks 0..63  : wt12[64][256] bf16 = [w1|w2]^T
// blocks 64..191: woutT[z][cd] bf16
__global__ __launch_bounds__(256) void k_prep(const float* __restrict__ w1,
                                              const float* __restrict__ w2,
                                              const float* __restrict__ wout,
                                              __hip_bfloat16* __restrict__ wt12,
                                              __hip_bfloat16* __restrict__ woutT)
{
    const int b = blockIdx.x, t = threadIdx.x;
    if (b < 64) {
        const float* w = (b < CH) ? w1 : w2;
        wt12[b * CM + t] = __float2bfloat16(w[(size_t)t * CH + (b & 31)]);
    } else {
        const int z = b - 64;
        for (int cd = t; cd < CH*CH; cd += 256)
            woutT[(size_t)z * (CH*CH) + cd] = __float2bfloat16(wout[(size_t)cd * CZ + z]);
    }
}

// ---- Kernel 1: LayerNorm + dual projection via MFMA (unchanged) ----------
#define LNR 264
__global__ __launch_bounds__(256) void k_lnp(
    const float* __restrict__ m, const float* __restrict__ mask,
    const float* __restrict__ gamma, const float* __restrict__ beta,
    const float* __restrict__ b1, const float* __restrict__ b2,
    const __hip_bfloat16* __restrict__ wt12,
    __hip_bfloat16* __restrict__ At, __hip_bfloat16* __restrict__ Bt)
{
    __shared__ __hip_bfloat16 lnS[128 * LNR];
    __shared__ float msk[128];
    const int n0 = blockIdx.x * 16, s0 = blockIdx.y * 8;
    const int t = threadIdx.x, wave = t >> 6, lane = t & 63;
    const int l15 = lane & 15, quad = lane >> 4;

    if (t < 128) msk[t] = mask[(s0 + (t & 7))*N_ + n0 + (t >> 3)];

    float4 g  = ((const float4*)gamma)[lane];
    float4 be = ((const float4*)beta)[lane];
    for (int i = 0; i < 32; ++i) {
        const int row = wave*32 + i;
        const int n = row >> 3, s = row & 7;
        float4 x = ((const float4*)(m + ((size_t)((s0+s)*N_ + n0 + n)) * CM))[lane];
        float sum = x.x + x.y + x.z + x.w;
        float ssq = x.x*x.x + x.y*x.y + x.z*x.z + x.w*x.w;
        #pragma unroll
        for (int off = 32; off >= 1; off >>= 1) {
            sum += __shfl_xor(sum, off, 64);
            ssq += __shfl_xor(ssq, off, 64);
        }
        const float mean = sum * (1.0f/CM);
        const float var  = ssq * (1.0f/CM) - mean*mean;
        const float rstd = rsqrtf(var + 1e-5f);
        pack4 pk;
        pk.h[0] = __float2bfloat16((x.x - mean)*rstd*g.x + be.x);
        pk.h[1] = __float2bfloat16((x.y - mean)*rstd*g.y + be.y);
        pk.h[2] = __float2bfloat16((x.z - mean)*rstd*g.z + be.z);
        pk.h[3] = __float2bfloat16((x.w - mean)*rstd*g.w + be.w);
        *(uint2*)&lnS[row*LNR + lane*4] = pk.u;
    }
    __syncthreads();

    f32x4 acc[2][4];
    const f32x4 z4 = {0.f,0.f,0.f,0.f};
    #pragma unroll
    for (int mt = 0; mt < 2; ++mt)
        #pragma unroll
        for (int nt = 0; nt < 4; ++nt) acc[mt][nt] = z4;

    #pragma unroll
    for (int kk = 0; kk < 8; ++kk) {
        bf16x8 a0 = *(const bf16x8*)&lnS[(wave*32      + l15)*LNR + kk*32 + quad*8];
        bf16x8 a1 = *(const bf16x8*)&lnS[(wave*32 + 16 + l15)*LNR + kk*32 + quad*8];
        #pragma unroll
        for (int nt = 0; nt < 4; ++nt) {
            bf16x8 wv = *(const bf16x8*)&wt12[(size_t)(nt*16 + l15)*CM + kk*32 + quad*8];
            acc[0][nt] = __builtin_amdgcn_mfma_f32_16x16x32_bf16(a0, wv, acc[0][nt], 0,0,0);
            acc[1][nt] = __builtin_amdgcn_mfma_f32_16x16x32_bf16(a1, wv, acc[1][nt], 0,0,0);
        }
    }

    #pragma unroll
    for (int nt = 0; nt < 4; ++nt) {
        const int ncol = nt*16 + l15;
        const int sel = ncol >> 5, c = ncol & 31;
        const float bias = sel ? b2[c] : b1[c];
        __hip_bfloat16* dst = sel ? Bt : At;
        #pragma unroll
        for (int mt = 0; mt < 2; ++mt) {
            const int rowb = wave*32 + mt*16 + quad*4;
            const int n_loc = rowb >> 3, s_loc = rowb & 7;
            pack4 pk;
            #pragma unroll
            for (int r = 0; r < 4; ++r)
                pk.h[r] = __float2bfloat16((acc[mt][nt][r] + bias) * msk[rowb + r]);
            *(uint2*)&dst[((size_t)(n0 + n_loc)*CH + c)*S_ + s0 + s_loc] = pk.u;
        }
    }
}

// ---- Kernel 2: persistent fused outer-product + w_out GEMM ---------------
// 256 persistent blocks x 512 thr (8 waves, 2 waves/SIMD via launch_bounds).
// Each block walks 18 tiles of 8i x 4j (32 p-pairs). Per tile:
//   stage 2: M=256(8i,32c) x N=128(4j,32d), K=128(s); wave = 64x64 tile
//            (mq=wave&3 M-quarter, nh=wave>>2 N-half), acc 4x4 f32x4.
//   O in LDS: 32 rows x 2KB, XOR-swizzled chunks (16B chunk (c,q=d>>3) at
//            q*512 + ((c^(p&7))*16) bytes) -> conflict-free b64 writes and
//            b128 reads at the bank floor.
//   stage 3: wave owns exclusive 16-z slice; wf[32] woutT fragments loaded
//            ONCE at kernel start and persist across all 18 tiles
//            (128 VGPR; occupancy is structure-bound at 2 waves/SIMD anyway).
//   RN fused per-tile (32 mask dot products, shfl-reduced) -> no k_rnorm.
__global__ __launch_bounds__(512, 2) void k_opm(
    const __hip_bfloat16* __restrict__ At, const __hip_bfloat16* __restrict__ Bt,
    const float* __restrict__ mask, const __hip_bfloat16* __restrict__ woutT,
    const float* __restrict__ bout, float* __restrict__ out)
{
    __shared__ __hip_bfloat16 O[32 * 1024];   // 64 KB, swizzled
    __shared__ float RNl[32];
    const int t = threadIdx.x;
    const int wave = t >> 6, lane = t & 63;
    const int l15 = lane & 15, quad = lane >> 4;
    const int mq = wave & 3, nh = wave >> 2;

    // persistent per-wave state: 16-z slice of woutT + bias
    const int zb = wave * 16;
    bf16x8 wf[32];
    #pragma unroll
    for (int kk = 0; kk < 32; ++kk)
        wf[kk] = *(const bf16x8*)&woutT[(size_t)(zb + l15) * (CH*CH) + kk*32 + quad*8];
    const float bz = bout[zb + l15];

    const f32x4 z4 = {0.f,0.f,0.f,0.f};

    for (int tl = 0; tl < 18; ++tl) {
        const int tile = blockIdx.x * 18 + tl;          // 256*18 = 4608 tiles
        const int i0 = (tile / 96) * 8, j0 = (tile % 96) * 4;

        // ---- stage 2 ----
        f32x4 acc[4][4];
        #pragma unroll
        for (int nt = 0; nt < 4; ++nt)
            #pragma unroll
            for (int mt = 0; mt < 4; ++mt) acc[nt][mt] = z4;

        int aOff[4], bOff[4];
        #pragma unroll
        for (int mt = 0; mt < 4; ++mt) {
            const int Mrow = mq*64 + mt*16 + l15;       // = i_l*32 + c
            aOff[mt] = ((i0 + (Mrow >> 5)) * CH + (Mrow & 31)) * S_ + quad*8;
        }
        #pragma unroll
        for (int nt = 0; nt < 4; ++nt) {
            const int Ncol = nh*64 + nt*16 + l15;       // = j_l*32 + d
            bOff[nt] = ((j0 + (Ncol >> 5)) * CH + (Ncol & 31)) * S_ + quad*8;
        }

        #pragma unroll
        for (int kk = 0; kk < 4; ++kk) {
            bf16x8 af[4], bfr[4];
            #pragma unroll
            for (int mt = 0; mt < 4; ++mt) af[mt]  = *(const bf16x8*)&At[aOff[mt] + kk*32];
            #pragma unroll
            for (int nt = 0; nt < 4; ++nt) bfr[nt] = *(const bf16x8*)&Bt[bOff[nt] + kk*32];
            #pragma unroll
            for (int nt = 0; nt < 4; ++nt)
                #pragma unroll
                for (int mt = 0; mt < 4; ++mt)
                    acc[nt][mt] = __builtin_amdgcn_mfma_f32_16x16x32_bf16(
                        bfr[nt], af[mt], acc[nt][mt], 0, 0, 0);
        }

        // ---- fused RN: p = wave*4+quad owns pair (i0+p>>2, j0+p&3) ----
        {
            const int p = wave*4 + quad;
            const int ic = i0 + (p >> 2), jc = j0 + (p & 3);
            float a = 0.f;
            #pragma unroll
            for (int u = 0; u < 8; ++u) {
                const int s = l15*8 + u;
                a += mask[s*N_ + ic] * mask[s*N_ + jc];
            }
            a += __shfl_xor(a, 1, 64);
            a += __shfl_xor(a, 2, 64);
            a += __shfl_xor(a, 4, 64);
            a += __shfl_xor(a, 8, 64);
            if (l15 == 0) RNl[p] = 1.0f / (a + 1e-3f);
        }

        // ---- O writes: col(l15)->(i_l,c); row(quad,r)->(j_l,d), swizzled ----
        #pragma unroll
        for (int mt = 0; mt < 4; ++mt) {
            const int Mcol = mq*64 + mt*16 + l15;
            const int i_l = Mcol >> 5, c = Mcol & 31;
            #pragma unroll
            for (int nt = 0; nt < 4; ++nt) {
                const int Nrow = nh*64 + nt*16 + quad*4;
                const int j_l = Nrow >> 5, d0 = Nrow & 31;
                const int p = i_l*4 + j_l;              // uniform per (mt,nt)
                pack4 pk;
                #pragma unroll
                for (int r = 0; r < 4; ++r) pk.h[r] = __float2bfloat16(acc[nt][mt][r]);
                const int idx = p*1024 + (d0 >> 3)*256 + ((c ^ (p & 7)) << 3)
                              + ((d0 >> 2) & 1)*4;
                *(uint2*)&O[idx] = pk.u;
            }
        }
        __syncthreads();

        // ---- stage 3: 32p x 16z per wave, K=1024, wf persistent ----
        f32x4 oacc[2];
        oacc[0] = z4; oacc[1] = z4;
        #pragma unroll
        for (int kk = 0; kk < 32; ++kk) {
            #pragma unroll
            for (int mt2 = 0; mt2 < 2; ++mt2) {
                const int row = mt2*16 + l15;
                bf16x8 a = *(const bf16x8*)&O[row*1024 + quad*256
                                              + ((kk ^ (row & 7)) << 3)];
                oacc[mt2] = __builtin_amdgcn_mfma_f32_16x16x32_bf16(
                    a, wf[kk], oacc[mt2], 0, 0, 0);
            }
        }

        // ---- epilogue: col(l15)->z, row(quad,r)->p; nontemporal stores ----
        #pragma unroll
        for (int mt2 = 0; mt2 < 2; ++mt2) {
            #pragma unroll
            for (int r = 0; r < 4; ++r) {
                const int p = mt2*16 + quad*4 + r;
                const int i = i0 + (p >> 2), j = j0 + (p & 3);
                __builtin_nontemporal_store((oacc[mt2][r] + bz) * RNl[p],
                    &out[((size_t)(i*N_ + j))*CZ + zb + l15]);
            }
        }
        __syncthreads();   // protect O/RNl before next tile's writes
    }
}

extern "C" void kernel_launch(void* const* d_in, const int* in_sizes, int n_in,
                              void* d_out, int out_size, void* d_ws, size_t ws_size,
                              hipStream_t stream)
{
    const float* m    = (const float*)d_in[0];
    const float* mask = (const float*)d_in[1];
    const float* gam  = (const float*)d_in[2];
    const float* bet  = (const float*)d_in[3];
    const float* w1   = (const float*)d_in[4];
    const float* b1   = (const float*)d_in[5];
    const float* w2   = (const float*)d_in[6];
    const float* b2   = (const float*)d_in[7];
    const float* wout = (const float*)d_in[8];
    const float* bout = (const float*)d_in[9];
    float* out = (float*)d_out;

    __hip_bfloat16* At    = (__hip_bfloat16*)d_ws;                 // [N][CH][S]
    __hip_bfloat16* Bt    = At + (size_t)N_ * CH * S_;             // [N][CH][S]
    __hip_bfloat16* woutT = Bt + (size_t)N_ * CH * S_;             // [CZ][1024]
    __hip_bfloat16* wt12  = woutT + (size_t)CZ * CH * CH;          // [64][256]

    k_prep<<<192, 256, 0, stream>>>(w1, w2, wout, wt12, woutT);
    dim3 gl(24, 16);
    k_lnp<<<gl, 256, 0, stream>>>(m, mask, gam, bet, b1, b2, wt12, At, Bt);
    k_opm<<<256, 512, 0, stream>>>(At, Bt, mask, woutT, bout, out);
}